// Round 1
// baseline (820.836 us; speedup 1.0000x reference)
//
#include <hip/hip_runtime.h>
#include <math.h>

#define TDIM 1024
#define DDIM 256
#define BDIM 64

// ---------------------------------------------------------------------------
// Kernel A: P[m][n] = sum_k x[m][k] * U[k][n] + bias[n]
//   M = B*T = 65536, N = K = 256.  BM=64, BN=256, BK=32, 256 threads,
//   8x8 micro-tile per thread. 4 blocks/CU (40KB LDS), 1024 blocks total.
// ---------------------------------------------------------------------------
__global__ __launch_bounds__(256)
void xu_gemm(const float* __restrict__ x, const float* __restrict__ U,
             const float* __restrict__ bias, float* __restrict__ P)
{
    __shared__ float As[32][64];   // [k][m] transposed A tile
    __shared__ float Bs[32][256];  // [k][n]
    const int tid = threadIdx.x;
    const int tr = tid >> 5;   // 0..7
    const int tc = tid & 31;   // 0..31
    const long rowBase = (long)blockIdx.x * 64;

    float acc[8][8];
#pragma unroll
    for (int r = 0; r < 8; ++r)
#pragma unroll
        for (int c = 0; c < 8; ++c) acc[r][c] = 0.f;

    for (int k0 = 0; k0 < 256; k0 += 32) {
        // stage A tile: 64 rows x 32 k = 512 float4, 2 per thread (transpose)
#pragma unroll
        for (int s = 0; s < 2; ++s) {
            int idx = tid * 2 + s;
            int r   = idx >> 3;          // 0..63
            int kq  = idx & 7;           // k-offset kq*4
            float4 v = *(const float4*)&x[(rowBase + r) * 256 + k0 + kq * 4];
            As[kq*4+0][r] = v.x;
            As[kq*4+1][r] = v.y;
            As[kq*4+2][r] = v.z;
            As[kq*4+3][r] = v.w;
        }
        // stage B tile: 32 x 256 = 2048 float4, 8 per thread
#pragma unroll
        for (int s = 0; s < 8; ++s) {
            int idx = tid + s * 256;
            int kk  = idx >> 6;
            int c4  = idx & 63;
            *(float4*)&Bs[kk][c4*4] = *(const float4*)&U[(k0 + kk) * 256 + c4*4];
        }
        __syncthreads();
#pragma unroll
        for (int kk = 0; kk < 32; ++kk) {
            float4 a0 = *(const float4*)&As[kk][tr*4];
            float4 a1 = *(const float4*)&As[kk][tr*4 + 32];
            float4 b0 = *(const float4*)&Bs[kk][tc*4];
            float4 b1 = *(const float4*)&Bs[kk][tc*4 + 128];
            float av[8] = {a0.x,a0.y,a0.z,a0.w,a1.x,a1.y,a1.z,a1.w};
            float bv[8] = {b0.x,b0.y,b0.z,b0.w,b1.x,b1.y,b1.z,b1.w};
#pragma unroll
            for (int r = 0; r < 8; ++r)
#pragma unroll
                for (int c = 0; c < 8; ++c)
                    acc[r][c] = fmaf(av[r], bv[c], acc[r][c]);
        }
        __syncthreads();
    }
    // epilogue: add bias, store
    float4 bb0 = *(const float4*)&bias[tc*4];
    float4 bb1 = *(const float4*)&bias[tc*4 + 128];
#pragma unroll
    for (int r = 0; r < 8; ++r) {
        long row = rowBase + (r < 4 ? (tr*4 + r) : (32 + tr*4 + (r - 4)));
        float4 lo = make_float4(acc[r][0] + bb0.x, acc[r][1] + bb0.y,
                                acc[r][2] + bb0.z, acc[r][3] + bb0.w);
        float4 hi = make_float4(acc[r][4] + bb1.x, acc[r][5] + bb1.y,
                                acc[r][6] + bb1.z, acc[r][7] + bb1.w);
        *(float4*)&P[row * 256 + tc*4]       = lo;
        *(float4*)&P[row * 256 + tc*4 + 128] = hi;
    }
}

// ---------------------------------------------------------------------------
// Kernel B: sequential scan. 1 block per batch row (64 blocks x 1024 thr).
//   W entirely in registers (float2 column-pairs -> pk-fma friendly),
//   state broadcast via LDS, 8-way K-split + LDS reduce, P prefetch.
//   P lives in the scan_out region (written by kernel A) and is overwritten
//   in place by the state history.
// ---------------------------------------------------------------------------
__global__ __launch_bounds__(1024)
void rnn_scan(const float* __restrict__ s0, const float* __restrict__ W,
              float* __restrict__ out)
{
    __shared__ float  s[256];
    __shared__ float2 red2[8][128];
    __shared__ float  pbuf[2][256];

    const int tid = threadIdx.x;
    const int q   = tid >> 7;    // 0..7  (k-quarter: k in [q*32, q*32+32))
    const int jp  = tid & 127;   // column pair index, j0 = 2*jp
    const int row = blockIdx.x;
    const int j0  = jp * 2;

    // W fragment in registers: 32 float2 = 64 VGPR
    float2 w[32];
#pragma unroll
    for (int i = 0; i < 32; ++i)
        w[i] = *(const float2*)&W[(q*32 + i) * 256 + j0];

    float* scanP = out + BDIM * DDIM + (long)row * TDIM * DDIM;

    if (tid < 64) {
        ((float4*)s)[tid]       = ((const float4*)(s0 + row * 256))[tid];
        ((float4*)pbuf[0])[tid] = ((const float4*)scanP)[tid];  // P[0]
    }
    __syncthreads();

    const float4* s4 = (const float4*)s;
    float4 pf;
    for (int t = 0; t < TDIM; ++t) {
        // issue prefetch of P[t+1] early (consumed next iteration)
        if (tid < 64) {
            int tn = (t + 1 < TDIM) ? t + 1 : TDIM - 1;
            pf = ((const float4*)(scanP + (long)tn * DDIM))[tid];
        }
        // partial dot: acc.x -> col j0, acc.y -> col j0+1
        float2 acc = make_float2(0.f, 0.f);
#pragma unroll
        for (int i8 = 0; i8 < 8; ++i8) {
            float4 sv = s4[q * 8 + i8];
            float sk[4] = {sv.x, sv.y, sv.z, sv.w};
#pragma unroll
            for (int u = 0; u < 4; ++u) {
                acc.x = fmaf(sk[u], w[i8*4 + u].x, acc.x);
                acc.y = fmaf(sk[u], w[i8*4 + u].y, acc.y);
            }
        }
        red2[q][jp] = acc;
        __syncthreads();

        if (tid < 256) {
            const float* redf = (const float*)red2;
            float z = pbuf[t & 1][tid];
#pragma unroll
            for (int qq = 0; qq < 8; ++qq) z += redf[qq * 256 + tid];
            float h = 1.f - 2.f / (1.f + __expf(2.f * z));
            s[tid] = h;
            scanP[(long)t * DDIM + tid] = h;            // scan_out
            if (t == TDIM - 1) out[row * DDIM + tid] = h;  // final_state
        }
        if (tid < 64) {
            ((float4*)pbuf[(t + 1) & 1])[tid] = pf;     // P[t+1] ready
        }
        __syncthreads();
    }
}

extern "C" void kernel_launch(void* const* d_in, const int* in_sizes, int n_in,
                              void* d_out, int out_size, void* d_ws, size_t ws_size,
                              hipStream_t stream) {
    (void)in_sizes; (void)n_in; (void)out_size; (void)d_ws; (void)ws_size;
    const float* s0 = (const float*)d_in[0];
    const float* x  = (const float*)d_in[1];
    const float* W  = (const float*)d_in[2];
    const float* U  = (const float*)d_in[3];
    const float* b  = (const float*)d_in[4];
    float* out = (float*)d_out;
    float* P   = out + BDIM * DDIM;   // scan_out region doubles as P buffer

    xu_gemm<<<dim3(65536 / 64), dim3(256), 0, stream>>>(x, U, b, P);
    rnn_scan<<<dim3(BDIM), dim3(1024), 0, stream>>>(s0, W, out);
}